// Round 3
// baseline (224.418 us; speedup 1.0000x reference)
//
#include <hip/hip_runtime.h>

typedef __attribute__((ext_vector_type(8))) short short8;
typedef __attribute__((ext_vector_type(4))) float floatx4;

#define CIN    192
#define COUTN  192
#define HWDIM  56
#define HWSZ   (56*56)
#define KWT    1728
#define PH     58
#define CK     32
#define NCHUNK 6

// ws layout: xpack [b 32][cc 6][h' 58][x' 58][c 32] bf16 ; wpack [og 3][cc 6][off 9][m 64][c 32] bf16
#define XPACK_SHORTS (32u*6u*58u*58u*32u)
#define WPACK_SHORTS (3u*6u*9u*64u*32u)
#define WS_NEEDED    ((size_t)(XPACK_SHORTS + WPACK_SHORTS) * 2u)

__device__ __forceinline__ short f2bf(float f) {
    union { float f; unsigned u; } v; v.f = f;
    unsigned u = v.u + 0x7FFFu + ((v.u >> 16) & 1u);  // RNE
    return (short)(u >> 16);
}

// ---------------- pack x: NCHW f32 -> padded [b][cc][h'][x'][c32] bf16, LDS transpose ----------------
__global__ __launch_bounds__(256)
void pack_x(const float* __restrict__ x, short* __restrict__ xp) {
    const int hq = blockIdx.x;   // 0..57 padded row
    const int cc = blockIdx.y;   // 0..5
    const int b  = blockIdx.z;   // 0..31
    const int tid = threadIdx.x;
    short* dst = xp + ((size_t)((b * 6 + cc) * 58 + hq) * 58) * CK;

    if (hq == 0 || hq == 57) {                 // zero pad rows: 232 chunks of 16B
        if (tid < 232) *(short8*)(dst + tid * 8) = (short8){0,0,0,0,0,0,0,0};
        return;
    }

    __shared__ unsigned lds[56 * 20];          // [px 56][cpair 16] stride 20 dwords (16B-aligned b128 reads)
    const int h = hq - 1;

    if (tid < 224) {                           // 16 cpairs x 14 float4-cols
        int cpair = tid / 14, f4 = tid % 14;
        const float* s1 = x + ((size_t)(b * CIN + cc * 32 + cpair * 2) * HWSZ) + h * 56 + f4 * 4;
        floatx4 v1 = *(const floatx4*)s1;
        floatx4 v2 = *(const floatx4*)(s1 + HWSZ);
#pragma unroll
        for (int k = 0; k < 4; ++k) {
            unsigned pr = (unsigned short)f2bf(v1[k]) | ((unsigned)(unsigned short)f2bf(v2[k]) << 16);
            lds[(f4 * 4 + k) * 20 + cpair] = pr;
        }
    }
    __syncthreads();
    if (tid < 232) {                           // emit 58 px x 4 chunks, coalesced
        int xq = tid >> 2, q = tid & 3;
        short8 v = (short8){0,0,0,0,0,0,0,0};
        if (xq >= 1 && xq <= 56)
            v = *(const short8*)&lds[(xq - 1) * 20 + q * 4];
        *(short8*)(dst + tid * 8) = v;
    }
}

// ---------------- pack weights to [og][cc][off][m 64][c 32] bf16 ----------------
__global__ __launch_bounds__(256)
void pack_w(const float* __restrict__ w, short* __restrict__ wp) {
    int idx = blockIdx.x * 256 + threadIdx.x;
    const int TOT = 3 * 6 * 9 * 64 * 4;
    if (idx >= TOT) return;
    int cg = idx & 3;
    int m  = (idx >> 2) & 63;
    int t  = idx >> 8;
    int off = t % 9;  t /= 9;
    int cc  = t % 6;
    int og  = t / 6;
    short8 v;
#pragma unroll
    for (int k = 0; k < 8; ++k)
        v[k] = f2bf(w[(size_t)(og * 64 + m) * KWT + (cc * 32 + cg * 8 + k) * 9 + off]);
    *(short8*)(wp + (size_t)idx * 8) = v;
}

// ---------------- main conv: m=64, n=448 (8 rows) per block, swizzled LDS ----------------
__global__ __launch_bounds__(256, 2)
void conv_main(const short* __restrict__ xp, const short* __restrict__ wp,
               const float* __restrict__ bias, float* __restrict__ out) {
    __shared__ __align__(16) short sh[10 * PH * CK];   // 37,120 B halo: 10 rows x 58 px x 32 ch

    const int tid  = threadIdx.x;
    const int gh0  = blockIdx.x * 8;       // 7 tiles of 8 output rows
    const int og   = blockIdx.y;           // 3 cout groups of 64
    const int bb   = blockIdx.z;
    const int lane = tid & 63;
    const int wave = tid >> 6;             // 4 waves split n: 112 px each (2 rows)
    const int g    = lane >> 4;
    const int col  = lane & 15;

    int pb[7];                             // halo pixel base (ly*58+lx) per n-tile
#pragma unroll
    for (int nt = 0; nt < 7; ++nt) {
        int l = wave * 112 + nt * 16 + col;
        pb[nt] = (l / 56) * PH + (l % 56);
    }

    floatx4 acc[4][7];
#pragma unroll
    for (int mt = 0; mt < 4; ++mt)
#pragma unroll
        for (int nt = 0; nt < 7; ++nt)
            acc[mt][nt] = (floatx4){0.f, 0.f, 0.f, 0.f};

    const short8* wpk = (const short8*)wp;

    for (int cc = 0; cc < NCHUNK; ++cc) {
        if (cc) __syncthreads();

        // stage 10x58 halo (2320 chunks of 16B) with inverse bank-swizzle on the SOURCE index:
        // data chunk (p, q) lands at LDS slot p*4 + (q ^ ((p>>1)&3))
        const short* src = xp + ((size_t)(bb * 6 + cc) * (PH * PH) + (size_t)gh0 * PH) * CK;
#pragma unroll
        for (int j = 0; j < 10; ++j) {
            int idx = j * 256 + tid;
            if (idx < 2320) {
                int p  = idx >> 2, sg = idx & 3;
                int gc = (p << 2) | (sg ^ ((p >> 1) & 3));
                __builtin_amdgcn_global_load_lds(
                    (const __attribute__((address_space(1))) void*)(src + (size_t)gc * 8),
                    (__attribute__((address_space(3))) void*)(sh + (j * 256 + wave * 64) * 8),
                    16, 0, 0);
            }
        }
        __syncthreads();

        const int wb = (og * 6 + cc) * 9 * 256;
#pragma unroll
        for (int off = 0; off < 9; ++off) {
            const int di = off / 3, dj = off % 3;
            short8 afr[4];
#pragma unroll
            for (int mt = 0; mt < 4; ++mt)      // coalesced L2-hit dwordx4
                afr[mt] = wpk[wb + off * 256 + (mt * 16 + col) * 4 + g];
#pragma unroll
            for (int nt = 0; nt < 7; ++nt) {
                int p  = pb[nt] + di * PH + dj;
                int ch = (p << 2) | (g ^ ((p >> 1) & 3));
                short8 bfr = *(const short8*)&sh[ch * 8];
                acc[0][nt] = __builtin_amdgcn_mfma_f32_16x16x32_bf16(afr[0], bfr, acc[0][nt], 0, 0, 0);
                acc[1][nt] = __builtin_amdgcn_mfma_f32_16x16x32_bf16(afr[1], bfr, acc[1][nt], 0, 0, 0);
                acc[2][nt] = __builtin_amdgcn_mfma_f32_16x16x32_bf16(afr[2], bfr, acc[2][nt], 0, 0, 0);
                acc[3][nt] = __builtin_amdgcn_mfma_f32_16x16x32_bf16(afr[3], bfr, acc[3][nt], 0, 0, 0);
            }
        }
    }

    // epilogue: D row = g*4 + r, col = lane&15
#pragma unroll
    for (int mt = 0; mt < 4; ++mt) {
        int o = og * 64 + mt * 16 + g * 4;
        float b0 = bias[o], b1 = bias[o + 1], b2 = bias[o + 2], b3 = bias[o + 3];
#pragma unroll
        for (int nt = 0; nt < 7; ++nt) {
            int l  = wave * 112 + nt * 16 + col;
            int h  = gh0 + l / 56;
            int ww = l % 56;
            size_t base = ((size_t)(bb * COUTN + o) * HWDIM + h) * HWDIM + ww;
            floatx4 v = acc[mt][nt];
            out[base]                     = v[0] + b0;
            out[base + (size_t)HWSZ]      = v[1] + b1;
            out[base + (size_t)2 * HWSZ]  = v[2] + b2;
            out[base + (size_t)3 * HWSZ]  = v[3] + b3;
        }
    }
}

// ---------------- fallback if ws too small (round-1 structure, self-contained) ----------------
__global__ __launch_bounds__(256, 2)
void conv3x3_fb(const float* __restrict__ x, const float* __restrict__ w,
                const float* __restrict__ bias, float* __restrict__ out) {
    __shared__ __align__(16) short sh_halo[6 * 58 * 32];
    __shared__ __align__(16) short sh_w[9 * 64 * 32];
    const int tid = threadIdx.x;
    const int gh0 = blockIdx.x * 4;
    const int o0  = blockIdx.y * 64;
    const int bb  = blockIdx.z;
    const int lane = tid & 63, wave = tid >> 6;
    const int wm = wave >> 1, wn = wave & 1;
    const int g = lane >> 4, col = lane & 15;
    int ly[7], lx[7];
#pragma unroll
    for (int nt = 0; nt < 7; ++nt) {
        int l = wn * 112 + nt * 16 + col;
        ly[nt] = l / 56; lx[nt] = l % 56;
    }
    floatx4 acc[2][7];
#pragma unroll
    for (int mt = 0; mt < 2; ++mt)
#pragma unroll
        for (int nt = 0; nt < 7; ++nt) acc[mt][nt] = (floatx4){0.f,0.f,0.f,0.f};
    for (int cc = 0; cc < NCHUNK; ++cc) {
        const int c0 = cc * 32;
        if (cc) __syncthreads();
        for (int i = tid; i < 4 * 6 * 58; i += 256) {
            int xx = i % 58, r = i / 58, y = r % 6, cg = r / 6;
            int gh = gh0 + y - 1, gw = xx - 1;
            bool ok = ((unsigned)gh < 56u) & ((unsigned)gw < 56u);
            const float* src = x + ((size_t)(bb * CIN + c0 + cg * 8) * HWDIM + gh) * HWDIM + gw;
            short8 v;
#pragma unroll
            for (int k = 0; k < 8; ++k) v[k] = f2bf(ok ? src[k * HWSZ] : 0.f);
            *(short8*)&sh_halo[(y * 58 + xx) * 32 + ((cg ^ ((xx >> 1) & 3)) << 3)] = v;
        }
        for (int i = tid; i < 9 * 64 * 4; i += 256) {
            int cg = i & 3, off = (i >> 2) % 9, m = i / 36;
            const float* src = w + (size_t)(o0 + m) * KWT + (c0 + cg * 8) * 9 + off;
            short8 v;
#pragma unroll
            for (int k = 0; k < 8; ++k) v[k] = f2bf(src[k * 9]);
            *(short8*)&sh_w[(off * 64 + m) * 32 + ((cg ^ ((m >> 1) & 3)) << 3)] = v;
        }
        __syncthreads();
#pragma unroll
        for (int off = 0; off < 9; ++off) {
            const int di = off / 3, dj = off % 3;
            short8 a[2];
#pragma unroll
            for (int mt = 0; mt < 2; ++mt) {
                int m = wm * 32 + mt * 16 + col;
                a[mt] = *(const short8*)&sh_w[(off * 64 + m) * 32 + ((g ^ ((m >> 1) & 3)) << 3)];
            }
#pragma unroll
            for (int nt = 0; nt < 7; ++nt) {
                int yy = ly[nt] + di, xpp = lx[nt] + dj;
                short8 bfr = *(const short8*)&sh_halo[(yy * 58 + xpp) * 32 + ((g ^ ((xpp >> 1) & 3)) << 3)];
                acc[0][nt] = __builtin_amdgcn_mfma_f32_16x16x32_bf16(a[0], bfr, acc[0][nt], 0, 0, 0);
                acc[1][nt] = __builtin_amdgcn_mfma_f32_16x16x32_bf16(a[1], bfr, acc[1][nt], 0, 0, 0);
            }
        }
    }
#pragma unroll
    for (int mt = 0; mt < 2; ++mt) {
        int o = o0 + wm * 32 + mt * 16 + g * 4;
#pragma unroll
        for (int nt = 0; nt < 7; ++nt) {
            int l = wn * 112 + nt * 16 + col;
            int h = gh0 + l / 56, ww = l % 56;
            size_t base = ((size_t)(bb * COUTN + o) * HWDIM + h) * HWDIM + ww;
            floatx4 v = acc[mt][nt];
#pragma unroll
            for (int r2 = 0; r2 < 4; ++r2)
                out[base + (size_t)r2 * HWSZ] = v[r2] + bias[o + r2];
        }
    }
}

extern "C" void kernel_launch(void* const* d_in, const int* in_sizes, int n_in,
                              void* d_out, int out_size, void* d_ws, size_t ws_size,
                              hipStream_t stream) {
    const float* x  = (const float*)d_in[0];
    const float* wt = (const float*)d_in[1];
    const float* bi = (const float*)d_in[2];
    float* out = (float*)d_out;

    if (ws_size >= WS_NEEDED) {
        short* xpk = (short*)d_ws;
        short* wpk = xpk + XPACK_SHORTS;
        pack_x<<<dim3(58, 6, 32), 256, 0, stream>>>(x, xpk);
        {
            int tot = 3 * 6 * 9 * 64 * 4;
            pack_w<<<(tot + 255) / 256, 256, 0, stream>>>(wt, wpk);
        }
        conv_main<<<dim3(7, 3, 32), dim3(256), 0, stream>>>(xpk, wpk, bi, out);
    } else {
        conv3x3_fb<<<dim3(14, 3, 32), dim3(256), 0, stream>>>(x, wt, bi, out);
    }
}